// Round 1
// baseline (2458.719 us; speedup 1.0000x reference)
//
#include <hip/hip_runtime.h>
#include <hip/hip_fp16.h>
#include <stdint.h>

// BiLSTM 2-layer, B=64, T=1024, D=H=128.
// Strategy: fused scan. Per layer, 128 WGs = (2 dirs x 64 batch rows); each WG
// owns one independent recurrent sequence. All weights (Wih|Whh) live in VGPRs
// as packed f16x2 (v_dot2_f32_f16, fp32 accumulate). x and h staged in LDS as
// f16x2. Gates/c/h kept fp32. No xg materialization, no cross-WG sync.

#define T_SEQ 1024
#define B_SZ  64

typedef _Float16 h2_t __attribute__((ext_vector_type(2)));

__device__ inline float dot2(uint32_t a, uint32_t b, float c) {
  return __builtin_amdgcn_fdot2(__builtin_bit_cast(h2_t, a),
                                __builtin_bit_cast(h2_t, b), c, false);
}

__device__ inline uint32_t pack2(float a, float b) {
  uint16_t ua = __builtin_bit_cast(uint16_t, (_Float16)a);
  uint16_t ub = __builtin_bit_cast(uint16_t, (_Float16)b);
  return (uint32_t)ua | ((uint32_t)ub << 16);
}

__device__ inline float sigmoidf_fast(float z) {
  return 1.0f / (1.0f + __expf(-z));
}

__device__ inline float tanhf_fast(float z) {
  float e = __expf(-2.0f * fabsf(z));
  float r = (1.0f - e) / (1.0f + e);
  return copysignf(r, z);
}

// Pack one cell's weights: wdst[k2*512 + g] = f16x2 of (Wcat[g][2k2], Wcat[g][2k2+1])
// where Wcat = [Wih | Whh] (row g, K = din + 128). Also bias fold.
__global__ void prep_pack(const float* __restrict__ Wih, const float* __restrict__ Whh,
                          const float* __restrict__ bih, const float* __restrict__ bhh,
                          uint32_t* __restrict__ wdst, float* __restrict__ bdst, int din) {
  int idx = blockIdx.x * 256 + threadIdx.x;
  int kw2 = din / 2 + 64;
  int nw = kw2 * 512;
  if (idx < nw) {
    int k2 = idx >> 9, g = idx & 511;
    float a, b;
    if (k2 < din / 2) {
      a = Wih[g * din + 2 * k2];
      b = Wih[g * din + 2 * k2 + 1];
    } else {
      int kk = k2 - din / 2;
      a = Whh[g * 128 + 2 * kk];
      b = Whh[g * 128 + 2 * kk + 1];
    }
    wdst[idx] = pack2(a, b);
  } else if (idx < nw + 512) {
    int g = idx - nw;
    bdst[g] = bih[g] + bhh[g];
  }
}

// x [B,T,128] fp32 -> packed f16x2 [B,T,64] u32
__global__ void prep_x(const float2* __restrict__ x2, uint32_t* __restrict__ xf16) {
  int idx = blockIdx.x * 256 + threadIdx.x;  // < 64*1024*64
  float2 v = x2[idx];
  xf16[idx] = pack2(v.x, v.y);
}

// One layer (both directions). Block = 512 threads, thread g owns gate column g.
// blockIdx: b = blk & 63, dir = blk >> 6.
// xin: [B,T,DIN/2] u32 (f16x2). wpack: [2][KW2][512] u32. bias: [2][512] fp32.
// FINAL=false: write h as f16 into hout [B,T,256] u16 view at dir*128.
// FINAL=true : write h fp32 into fout [B,T,256] at dir*128.
template <int DIN, bool FINAL>
__global__ __launch_bounds__(512, 2) void scan_kernel(
    const uint32_t* __restrict__ xin, const uint32_t* __restrict__ wpack,
    const float* __restrict__ bias, uint32_t* __restrict__ hout,
    float* __restrict__ fout) {
  constexpr int KW2 = DIN / 2 + 64;  // packed words per gate row
  const int g = threadIdx.x;
  const int b = blockIdx.x & 63;
  const int dir = blockIdx.x >> 6;

  __shared__ __align__(16) uint32_t inbuf[2][KW2];  // [parity][ x(DIN/2) | h(64) ]
  __shared__ float gates[512];

  // Load this thread's weight row (stays in VGPRs: fully unrolled, const idx).
  uint32_t w[KW2];
  const uint32_t* wp = wpack + dir * KW2 * 512 + g;
#pragma unroll
  for (int k = 0; k < KW2; k++) w[k] = wp[k * 512];
  const float bias_g = bias[dir * 512 + g];

  // Init: h0 = 0 in both parities; preload x for first step.
  if (g < 64) {
    inbuf[0][DIN / 2 + g] = 0u;
    inbuf[1][DIN / 2 + g] = 0u;
  }
  const int t0 = dir ? (T_SEQ - 1) : 0;
  if (g < DIN / 2) inbuf[0][g] = xin[(b * T_SEQ + t0) * (DIN / 2) + g];
  float c = 0.0f;
  __syncthreads();

  for (int s = 0; s < T_SEQ; s++) {
    const int t = dir ? (T_SEQ - 1 - s) : s;
    const int par = s & 1;

    // Prefetch next x into regs (latency hidden under the dot phase).
    uint32_t xn = 0;
    if (g < DIN / 2 && s + 1 < T_SEQ) {
      const int tn = dir ? (t - 1) : (t + 1);
      xn = xin[(b * T_SEQ + tn) * (DIN / 2) + g];
    }

    // gates[g] = bias + sum_k [x|h]_k * Wcat[g]_k  (f16 pairs, fp32 accum)
    float acc = bias_g;
    const uint4* ib4 = (const uint4*)(&inbuf[par][0]);
#pragma unroll
    for (int k4 = 0; k4 < KW2 / 4; k4++) {
      uint4 v = ib4[k4];
      acc = dot2(v.x, w[4 * k4 + 0], acc);
      acc = dot2(v.y, w[4 * k4 + 1], acc);
      acc = dot2(v.z, w[4 * k4 + 2], acc);
      acc = dot2(v.w, w[4 * k4 + 3], acc);
    }

    // Activation: gate order i,f,g,o -> sigmoid except g-range [256,384) = tanh.
    float act = (g >= 256 && g < 384) ? tanhf_fast(acc) : sigmoidf_fast(acc);
    gates[g] = act;
    __syncthreads();  // gates ready; all reads of inbuf[par] h-region done

    if (g < 128) {
      float iv = gates[g], fv = gates[g + 128], gv = gates[g + 256], ov = gates[g + 384];
      c = fv * c + iv * gv;
      float h = ov * tanhf_fast(c);
      uint16_t hu = __builtin_bit_cast(uint16_t, (_Float16)h);
      // write h (f16) into both parities' h-region for the next step's dot
      ((uint16_t*)(&inbuf[0][DIN / 2]))[g] = hu;
      ((uint16_t*)(&inbuf[1][DIN / 2]))[g] = hu;
      if (FINAL) {
        fout[(b * T_SEQ + t) * 256 + dir * 128 + g] = h;
      } else {
        ((uint16_t*)hout)[(b * T_SEQ + t) * 256 + dir * 128 + g] = hu;
      }
    }
    if (g < DIN / 2 && s + 1 < T_SEQ) inbuf[par ^ 1][g] = xn;
    __syncthreads();  // h + next x visible
  }
}

extern "C" void kernel_launch(void* const* d_in, const int* in_sizes, int n_in,
                              void* d_out, int out_size, void* d_ws, size_t ws_size,
                              hipStream_t stream) {
  const float* x = (const float*)d_in[0];
  // d_in order: x, lengths, then (Wih,Whh,bih,bhh) for fw1,bw1,fw2,bw2
  const float* Wih_fw1 = (const float*)d_in[2];
  const float* Whh_fw1 = (const float*)d_in[3];
  const float* bih_fw1 = (const float*)d_in[4];
  const float* bhh_fw1 = (const float*)d_in[5];
  const float* Wih_bw1 = (const float*)d_in[6];
  const float* Whh_bw1 = (const float*)d_in[7];
  const float* bih_bw1 = (const float*)d_in[8];
  const float* bhh_bw1 = (const float*)d_in[9];
  const float* Wih_fw2 = (const float*)d_in[10];
  const float* Whh_fw2 = (const float*)d_in[11];
  const float* bih_fw2 = (const float*)d_in[12];
  const float* bhh_fw2 = (const float*)d_in[13];
  const float* Wih_bw2 = (const float*)d_in[14];
  const float* Whh_bw2 = (const float*)d_in[15];
  const float* bih_bw2 = (const float*)d_in[16];
  const float* bhh_bw2 = (const float*)d_in[17];

  uint8_t* ws = (uint8_t*)d_ws;
  // ws layout (bytes):
  //   0        : wpack1  [2][128][512] u32  (512 KB)
  //   524288   : wpack2  [2][192][512] u32  (768 KB)
  //   1310720  : bias    [4][512] fp32      (8 KB)
  //   2097152  : xf16    [B,T,64] u32       (16 MB)
  //   18874368 : out1f16 [B,T,128] u32      (32 MB)   total ~50 MB
  uint32_t* wpack1 = (uint32_t*)(ws + 0);
  uint32_t* wpack2 = (uint32_t*)(ws + 524288);
  float* biasws = (float*)(ws + 1310720);
  uint32_t* xf16 = (uint32_t*)(ws + 2097152);
  uint32_t* out1 = (uint32_t*)(ws + 18874368);
  float* fout = (float*)d_out;

  // Weight/bias packing (4 cells). KW2_1=128 -> 65536+512 items; KW2_2=192 -> 98304+512.
  {
    int n1 = 128 * 512 + 512, n2 = 192 * 512 + 512;
    prep_pack<<<(n1 + 255) / 256, 256, 0, stream>>>(Wih_fw1, Whh_fw1, bih_fw1, bhh_fw1,
                                                    wpack1, biasws, 128);
    prep_pack<<<(n1 + 255) / 256, 256, 0, stream>>>(Wih_bw1, Whh_bw1, bih_bw1, bhh_bw1,
                                                    wpack1 + 128 * 512, biasws + 512, 128);
    prep_pack<<<(n2 + 255) / 256, 256, 0, stream>>>(Wih_fw2, Whh_fw2, bih_fw2, bhh_fw2,
                                                    wpack2, biasws + 1024, 256);
    prep_pack<<<(n2 + 255) / 256, 256, 0, stream>>>(Wih_bw2, Whh_bw2, bih_bw2, bhh_bw2,
                                                    wpack2 + 192 * 512, biasws + 1536, 256);
  }
  // x -> f16x2
  prep_x<<<(B_SZ * T_SEQ * 64) / 256, 256, 0, stream>>>((const float2*)x, xf16);

  // Layer 1: reads xf16, writes out1 (f16). Layer 2: reads out1, writes d_out fp32.
  scan_kernel<128, false><<<128, 512, 0, stream>>>(xf16, wpack1, biasws, out1, nullptr);
  scan_kernel<256, true><<<128, 512, 0, stream>>>(out1, wpack2, biasws + 1024, nullptr, fout);
}

// Round 2
// 2423.081 us; speedup vs baseline: 1.0147x; 1.0147x over previous
//
#include <hip/hip_runtime.h>
#include <hip/hip_fp16.h>
#include <stdint.h>

// BiLSTM 2-layer, B=64, T=1024, D=H=128.
// Round 2: weights forced into VGPRs via ext_vector_type (round 1's w[] array
// fell to scratch -> L2-bound weight re-fetch every step, 51 GB from L2).
// Layout: 128 WGs (2 dir x 64 batch) x 512 threads. Thread (j,p) j in [0,128),
// p in [0,4) computes all 4 gate rows {j,j+128q} over K-span p: 4 independent
// fp32 accumulators (ILP), LDS-broadcast input reused 4x. 2 barriers/step.

#define T_SEQ 1024
#define B_SZ  64

typedef _Float16 h2_t __attribute__((ext_vector_type(2)));
typedef uint32_t v32u __attribute__((ext_vector_type(32)));
typedef uint32_t v48u __attribute__((ext_vector_type(48)));
template <int N> struct WV;
template <> struct WV<32> { using type = v32u; };
template <> struct WV<48> { using type = v48u; };

__device__ inline float dot2(uint32_t a, uint32_t b, float c) {
  return __builtin_amdgcn_fdot2(__builtin_bit_cast(h2_t, a),
                                __builtin_bit_cast(h2_t, b), c, false);
}

__device__ inline uint32_t pack2(float a, float b) {
  uint16_t ua = __builtin_bit_cast(uint16_t, (_Float16)a);
  uint16_t ub = __builtin_bit_cast(uint16_t, (_Float16)b);
  return (uint32_t)ua | ((uint32_t)ub << 16);
}

__device__ inline float sigmoidf_fast(float z) { return 1.0f / (1.0f + __expf(-z)); }

__device__ inline float tanhf_fast(float z) {
  float e = __expf(-2.0f * fabsf(z));
  float r = (1.0f - e) / (1.0f + e);
  return copysignf(r, z);
}

// wdst[w2*512 + g] = f16x2 of (Wcat[g][2*w2], Wcat[g][2*w2+1]), Wcat=[Wih|Whh].
__global__ void prep_pack(const float* __restrict__ Wih, const float* __restrict__ Whh,
                          const float* __restrict__ bih, const float* __restrict__ bhh,
                          uint32_t* __restrict__ wdst, float* __restrict__ bdst, int din) {
  int idx = blockIdx.x * 256 + threadIdx.x;
  int kw2 = din / 2 + 64;
  int nw = kw2 * 512;
  if (idx < nw) {
    int k2 = idx >> 9, g = idx & 511;
    float a, b;
    if (k2 < din / 2) {
      a = Wih[g * din + 2 * k2];
      b = Wih[g * din + 2 * k2 + 1];
    } else {
      int kk = k2 - din / 2;
      a = Whh[g * 128 + 2 * kk];
      b = Whh[g * 128 + 2 * kk + 1];
    }
    wdst[idx] = pack2(a, b);
  } else if (idx < nw + 512) {
    int g = idx - nw;
    bdst[g] = bih[g] + bhh[g];
  }
}

__global__ void prep_x(const float2* __restrict__ x2, uint32_t* __restrict__ xf16) {
  int idx = blockIdx.x * 256 + threadIdx.x;
  float2 v = x2[idx];
  xf16[idx] = pack2(v.x, v.y);
}

// One layer, both dirs. Block 512: thread (j = tid&127, p = tid>>7).
// xin: [B,T,DIN/2] u32 f16x2. wpack: [2][KW2][512] u32. bias: [2][512] f32.
template <int DIN, bool FINAL>
__global__ __launch_bounds__(512, 2) void scan_kernel(
    const uint32_t* __restrict__ xin, const uint32_t* __restrict__ wpack,
    const float* __restrict__ bias, uint32_t* __restrict__ hout,
    float* __restrict__ fout) {
  constexpr int KW2 = DIN / 2 + 64;   // packed words per gate row
  constexpr int SPAN = KW2 / 4;       // words per thread per row
  constexpr int XW = DIN / 2;         // x words (h region at [XW, KW2))
  using wv = typename WV<SPAN>::type;

  const int tid = threadIdx.x;
  const int j = tid & 127;
  const int p = tid >> 7;
  const int b = blockIdx.x & 63;
  const int dir = blockIdx.x >> 6;

  __shared__ __align__(16) uint32_t inbuf[2][KW2];  // [parity][ x | h ] f16x2
  __shared__ float psum[16][128];                   // [q*4+p][j]

  // Per-thread weights: 4 gate rows x SPAN words, as ext vectors (SSA -> VGPRs).
  wv wa, wb, wc, wd;
  {
    const uint32_t* wp = wpack + dir * KW2 * 512 + j;
#pragma unroll
    for (int k = 0; k < SPAN; k++) {
      int w2i = (p * SPAN + k) * 512;
      wa[k] = wp[w2i];
      wb[k] = wp[w2i + 128];
      wc[k] = wp[w2i + 256];
      wd[k] = wp[w2i + 384];
    }
  }
  float b0 = bias[dir * 512 + j];
  float b1 = bias[dir * 512 + 128 + j];
  float b2 = bias[dir * 512 + 256 + j];
  float b3 = bias[dir * 512 + 384 + j];

  // Init parity 0: x(t0) + h0 = 0.
  const int t0 = dir ? (T_SEQ - 1) : 0;
  if (tid < XW) inbuf[0][tid] = xin[(b * T_SEQ + t0) * XW + tid];
  if (tid >= XW && tid < KW2) inbuf[0][tid] = 0u;
  if (tid < 64) inbuf[0][XW + tid] = 0u;  // covers h region when XW+64 <= 512
  float c = 0.0f;
  __syncthreads();

  for (int s = 0; s < T_SEQ; s++) {
    const int t = dir ? (T_SEQ - 1 - s) : s;
    const int par = s & 1;

    // Prefetch next x into regs (p==1 group owns the store later).
    uint32_t xn = 0;
    if (p == 1 && j < XW && s + 1 < T_SEQ) {
      const int tn = dir ? (t - 1) : (t + 1);
      xn = xin[(b * T_SEQ + tn) * XW + j];
    }

    // 4 partial dots over this thread's K-span (broadcast LDS reads, reused 4x).
    float a0 = 0.f, a1 = 0.f, a2 = 0.f, a3 = 0.f;
    const uint4* ib = (const uint4*)(&inbuf[par][p * SPAN]);
#pragma unroll
    for (int kk = 0; kk < SPAN / 4; kk++) {
      uint4 v = ib[kk];
      a0 = dot2(v.x, wa[4 * kk + 0], a0);
      a1 = dot2(v.x, wb[4 * kk + 0], a1);
      a2 = dot2(v.x, wc[4 * kk + 0], a2);
      a3 = dot2(v.x, wd[4 * kk + 0], a3);
      a0 = dot2(v.y, wa[4 * kk + 1], a0);
      a1 = dot2(v.y, wb[4 * kk + 1], a1);
      a2 = dot2(v.y, wc[4 * kk + 1], a2);
      a3 = dot2(v.y, wd[4 * kk + 1], a3);
      a0 = dot2(v.z, wa[4 * kk + 2], a0);
      a1 = dot2(v.z, wb[4 * kk + 2], a1);
      a2 = dot2(v.z, wc[4 * kk + 2], a2);
      a3 = dot2(v.z, wd[4 * kk + 2], a3);
      a0 = dot2(v.w, wa[4 * kk + 3], a0);
      a1 = dot2(v.w, wb[4 * kk + 3], a1);
      a2 = dot2(v.w, wc[4 * kk + 3], a2);
      a3 = dot2(v.w, wd[4 * kk + 3], a3);
    }
    psum[0 * 4 + p][j] = a0;
    psum[1 * 4 + p][j] = a1;
    psum[2 * 4 + p][j] = a2;
    psum[3 * 4 + p][j] = a3;
    __syncthreads();  // psums ready; all inbuf[par] reads done

    if (p == 1 && j < XW && s + 1 < T_SEQ) {
      inbuf[par ^ 1][j] = xn;  // x region of other parity (nobody reads it now)
    }
    if (p == 0) {
      float ti = b0 + psum[0][j] + psum[1][j] + psum[2][j] + psum[3][j];
      float tf = b1 + psum[4][j] + psum[5][j] + psum[6][j] + psum[7][j];
      float tg = b2 + psum[8][j] + psum[9][j] + psum[10][j] + psum[11][j];
      float to = b3 + psum[12][j] + psum[13][j] + psum[14][j] + psum[15][j];
      float iv = sigmoidf_fast(ti);
      float fv = sigmoidf_fast(tf);
      float gv = tanhf_fast(tg);
      float ov = sigmoidf_fast(to);
      c = fv * c + iv * gv;
      float h = ov * tanhf_fast(c);
      uint16_t hu = __builtin_bit_cast(uint16_t, (_Float16)h);
      ((uint16_t*)(&inbuf[par ^ 1][XW]))[j] = hu;  // h for next step's parity
      if (FINAL) {
        fout[(b * T_SEQ + t) * 256 + dir * 128 + j] = h;
      } else {
        ((uint16_t*)hout)[(b * T_SEQ + t) * 256 + dir * 128 + j] = hu;
      }
    }
    __syncthreads();  // h + next-x visible before next dot phase
  }
}

extern "C" void kernel_launch(void* const* d_in, const int* in_sizes, int n_in,
                              void* d_out, int out_size, void* d_ws, size_t ws_size,
                              hipStream_t stream) {
  const float* x = (const float*)d_in[0];
  const float* Wih_fw1 = (const float*)d_in[2];
  const float* Whh_fw1 = (const float*)d_in[3];
  const float* bih_fw1 = (const float*)d_in[4];
  const float* bhh_fw1 = (const float*)d_in[5];
  const float* Wih_bw1 = (const float*)d_in[6];
  const float* Whh_bw1 = (const float*)d_in[7];
  const float* bih_bw1 = (const float*)d_in[8];
  const float* bhh_bw1 = (const float*)d_in[9];
  const float* Wih_fw2 = (const float*)d_in[10];
  const float* Whh_fw2 = (const float*)d_in[11];
  const float* bih_fw2 = (const float*)d_in[12];
  const float* bhh_fw2 = (const float*)d_in[13];
  const float* Wih_bw2 = (const float*)d_in[14];
  const float* Whh_bw2 = (const float*)d_in[15];
  const float* bih_bw2 = (const float*)d_in[16];
  const float* bhh_bw2 = (const float*)d_in[17];

  uint8_t* ws = (uint8_t*)d_ws;
  // ws: wpack1 [2][128][512] u32 (512KB) | wpack2 [2][192][512] u32 (768KB) |
  //     bias [4][512] f32 (8KB) | xf16 [B,T,64] u32 (16MB) | out1 [B,T,128] u32 (32MB)
  uint32_t* wpack1 = (uint32_t*)(ws + 0);
  uint32_t* wpack2 = (uint32_t*)(ws + 524288);
  float* biasws = (float*)(ws + 1310720);
  uint32_t* xf16 = (uint32_t*)(ws + 2097152);
  uint32_t* out1 = (uint32_t*)(ws + 18874368);
  float* fout = (float*)d_out;

  int n1 = 128 * 512 + 512, n2 = 192 * 512 + 512;
  prep_pack<<<(n1 + 255) / 256, 256, 0, stream>>>(Wih_fw1, Whh_fw1, bih_fw1, bhh_fw1,
                                                  wpack1, biasws, 128);
  prep_pack<<<(n1 + 255) / 256, 256, 0, stream>>>(Wih_bw1, Whh_bw1, bih_bw1, bhh_bw1,
                                                  wpack1 + 128 * 512, biasws + 512, 128);
  prep_pack<<<(n2 + 255) / 256, 256, 0, stream>>>(Wih_fw2, Whh_fw2, bih_fw2, bhh_fw2,
                                                  wpack2, biasws + 1024, 256);
  prep_pack<<<(n2 + 255) / 256, 256, 0, stream>>>(Wih_bw2, Whh_bw2, bih_bw2, bhh_bw2,
                                                  wpack2 + 192 * 512, biasws + 1536, 256);
  prep_x<<<(B_SZ * T_SEQ * 64) / 256, 256, 0, stream>>>((const float2*)x, xf16);

  scan_kernel<128, false><<<128, 512, 0, stream>>>(xf16, wpack1, biasws, out1, nullptr);
  scan_kernel<256, true><<<128, 512, 0, stream>>>(out1, wpack2, biasws + 1024, nullptr, fout);
}

// Round 4
// 2289.517 us; speedup vs baseline: 1.0739x; 1.0583x over previous
//
#include <hip/hip_runtime.h>
#include <hip/hip_fp16.h>
#include <stdint.h>

// BiLSTM 2-layer, B=64, T=1024, D=H=128.
// Round 4: force weight residency with SCALAR asm barriers ("+v" on uint32_t;
// round 3's "+v"(uint4) hit 'tied indirect register inputs' -- aggregates are
// unsupported). Also 3-phase step: dot -> per-gate activation on all 512
// threads -> c/h update on p==0, so the transcendental tail runs on 8 waves
// instead of 2.
// Layout: 128 WGs (2 dir x 64 batch) x 512 thr; thread (j=tid&127, p=tid>>7)
// holds 4 gate rows {j+128r} over K-span p in VGPRs (f16x2, dot2 fp32-accum).

#define T_SEQ 1024
#define B_SZ  64

typedef _Float16 h2_t __attribute__((ext_vector_type(2)));

__device__ inline float dot2(uint32_t a, uint32_t b, float c) {
  return __builtin_amdgcn_fdot2(__builtin_bit_cast(h2_t, a),
                                __builtin_bit_cast(h2_t, b), c, false);
}

__device__ inline uint32_t pack2(float a, float b) {
  uint16_t ua = __builtin_bit_cast(uint16_t, (_Float16)a);
  uint16_t ub = __builtin_bit_cast(uint16_t, (_Float16)b);
  return (uint32_t)ua | ((uint32_t)ub << 16);
}

__device__ inline float sigmoidf_fast(float z) { return 1.0f / (1.0f + __expf(-z)); }

__device__ inline float tanhf_fast(float z) {
  float e = __expf(-2.0f * fabsf(z));
  float r = (1.0f - e) / (1.0f + e);
  return copysignf(r, z);
}

// wdst[w2*512 + g] = f16x2 of (Wcat[g][2*w2], Wcat[g][2*w2+1]), Wcat=[Wih|Whh].
__global__ void prep_pack(const float* __restrict__ Wih, const float* __restrict__ Whh,
                          const float* __restrict__ bih, const float* __restrict__ bhh,
                          uint32_t* __restrict__ wdst, float* __restrict__ bdst, int din) {
  int idx = blockIdx.x * 256 + threadIdx.x;
  int kw2 = din / 2 + 64;
  int nw = kw2 * 512;
  if (idx < nw) {
    int k2 = idx >> 9, g = idx & 511;
    float a, b;
    if (k2 < din / 2) {
      a = Wih[g * din + 2 * k2];
      b = Wih[g * din + 2 * k2 + 1];
    } else {
      int kk = k2 - din / 2;
      a = Whh[g * 128 + 2 * kk];
      b = Whh[g * 128 + 2 * kk + 1];
    }
    wdst[idx] = pack2(a, b);
  } else if (idx < nw + 512) {
    int g = idx - nw;
    bdst[g] = bih[g] + bhh[g];
  }
}

__global__ void prep_x(const float2* __restrict__ x2, uint32_t* __restrict__ xf16) {
  int idx = blockIdx.x * 256 + threadIdx.x;
  float2 v = x2[idx];
  xf16[idx] = pack2(v.x, v.y);
}

// One layer, both dirs. Block 512: thread (j = tid&127, p = tid>>7).
// xin: [B,T,DIN/2] u32 f16x2. wpack: [2][KW2][512] u32. bias: [2][512] f32.
template <int DIN, bool FINAL>
__global__ __launch_bounds__(512, 2) void scan_kernel(
    const uint32_t* __restrict__ xin, const uint32_t* __restrict__ wpack,
    const float* __restrict__ bias, uint32_t* __restrict__ hout,
    float* __restrict__ fout) {
  constexpr int KW2 = DIN / 2 + 64;   // packed words per gate row
  constexpr int SPAN = KW2 / 4;       // words per thread per row
  constexpr int NQ = SPAN / 4;        // uint4 quads per row span
  constexpr int XW = DIN / 2;         // x words (h region at [XW, KW2))

  const int tid = threadIdx.x;
  const int j = tid & 127;
  const int p = tid >> 7;
  const int b = blockIdx.x & 63;
  const int dir = blockIdx.x >> 6;

  __shared__ __align__(16) uint32_t inbuf[2][KW2];  // [parity][ x | h ] f16x2
  __shared__ float psum[16][128];                   // [r*4+p][j]
  __shared__ float gatesL[4][128];                  // [gate q][j] activations

  // Per-thread weights: 4 gate rows x NQ quads. Loaded once, then pinned in
  // VGPRs via empty scalar asm barriers -- afterwards the values are opaque
  // SSA defs the compiler cannot rematerialize by re-loading in the loop.
  uint4 wq[4][NQ];
  {
    const uint32_t* wp = wpack + (dir * KW2 + p * SPAN) * 512 + j;
#pragma unroll
    for (int r = 0; r < 4; r++) {
#pragma unroll
      for (int k = 0; k < NQ; k++) {
        wq[r][k].x = wp[(4 * k + 0) * 512 + r * 128];
        wq[r][k].y = wp[(4 * k + 1) * 512 + r * 128];
        wq[r][k].z = wp[(4 * k + 2) * 512 + r * 128];
        wq[r][k].w = wp[(4 * k + 3) * 512 + r * 128];
      }
    }
  }
#pragma unroll
  for (int r = 0; r < 4; r++)
#pragma unroll
    for (int k = 0; k < NQ; k++)
      asm volatile("" : "+v"(wq[r][k].x), "+v"(wq[r][k].y),
                        "+v"(wq[r][k].z), "+v"(wq[r][k].w));

  const float bias_pg = bias[dir * 512 + p * 128 + j];  // bias of gate p, row j

  // Init parity 0: x(t0) + h0 = 0.
  const int t0 = dir ? (T_SEQ - 1) : 0;
  if (tid < XW) inbuf[0][tid] = xin[(b * T_SEQ + t0) * XW + tid];
  if (tid >= XW && tid < KW2) inbuf[0][tid] = 0u;
  float c = 0.0f;
  __syncthreads();

  for (int s = 0; s < T_SEQ; s++) {
    const int t = dir ? (T_SEQ - 1 - s) : s;
    const int par = s & 1;

    // Prefetch next x into regs (p==1 group owns the store later).
    uint32_t xn = 0;
    if (p == 1 && j < XW && s + 1 < T_SEQ) {
      const int tn = dir ? (t - 1) : (t + 1);
      xn = xin[(b * T_SEQ + tn) * XW + j];
    }

    // Phase A: 4 partial dots over this thread's K-span (broadcast LDS reads).
    float a0 = 0.f, a1 = 0.f, a2 = 0.f, a3 = 0.f;
    const uint4* ib = (const uint4*)(&inbuf[par][p * SPAN]);
#pragma unroll
    for (int kk = 0; kk < NQ; kk++) {
      uint4 v = ib[kk];
      a0 = dot2(v.x, wq[0][kk].x, a0);
      a1 = dot2(v.x, wq[1][kk].x, a1);
      a2 = dot2(v.x, wq[2][kk].x, a2);
      a3 = dot2(v.x, wq[3][kk].x, a3);
      a0 = dot2(v.y, wq[0][kk].y, a0);
      a1 = dot2(v.y, wq[1][kk].y, a1);
      a2 = dot2(v.y, wq[2][kk].y, a2);
      a3 = dot2(v.y, wq[3][kk].y, a3);
      a0 = dot2(v.z, wq[0][kk].z, a0);
      a1 = dot2(v.z, wq[1][kk].z, a1);
      a2 = dot2(v.z, wq[2][kk].z, a2);
      a3 = dot2(v.z, wq[3][kk].z, a3);
      a0 = dot2(v.w, wq[0][kk].w, a0);
      a1 = dot2(v.w, wq[1][kk].w, a1);
      a2 = dot2(v.w, wq[2][kk].w, a2);
      a3 = dot2(v.w, wq[3][kk].w, a3);
    }
    psum[0 * 4 + p][j] = a0;
    psum[1 * 4 + p][j] = a1;
    psum[2 * 4 + p][j] = a2;
    psum[3 * 4 + p][j] = a3;
    __syncthreads();  // psums ready; all inbuf[par] reads done

    // Phase B: every thread reduces ONE gate (q = p) and applies activation.
    {
      float ssum = bias_pg + psum[p * 4 + 0][j] + psum[p * 4 + 1][j] +
                   psum[p * 4 + 2][j] + psum[p * 4 + 3][j];
      gatesL[p][j] = (p == 2) ? tanhf_fast(ssum) : sigmoidf_fast(ssum);
    }
    if (p == 1 && j < XW && s + 1 < T_SEQ) {
      inbuf[par ^ 1][j] = xn;  // x region of other parity (nobody reads it now)
    }
    __syncthreads();  // activations ready

    // Phase C: p==0 quarter updates c,h and writes h / output.
    if (p == 0) {
      float iv = gatesL[0][j], fv = gatesL[1][j], gv = gatesL[2][j], ov = gatesL[3][j];
      c = fv * c + iv * gv;
      float h = ov * tanhf_fast(c);
      uint16_t hu = __builtin_bit_cast(uint16_t, (_Float16)h);
      ((uint16_t*)(&inbuf[par ^ 1][XW]))[j] = hu;  // h for next step's parity
      if (FINAL) {
        fout[(b * T_SEQ + t) * 256 + dir * 128 + j] = h;
      } else {
        ((uint16_t*)hout)[(b * T_SEQ + t) * 256 + dir * 128 + j] = hu;
      }
    }
    __syncthreads();  // h + next-x visible before next dot phase
  }
}

extern "C" void kernel_launch(void* const* d_in, const int* in_sizes, int n_in,
                              void* d_out, int out_size, void* d_ws, size_t ws_size,
                              hipStream_t stream) {
  const float* x = (const float*)d_in[0];
  const float* Wih_fw1 = (const float*)d_in[2];
  const float* Whh_fw1 = (const float*)d_in[3];
  const float* bih_fw1 = (const float*)d_in[4];
  const float* bhh_fw1 = (const float*)d_in[5];
  const float* Wih_bw1 = (const float*)d_in[6];
  const float* Whh_bw1 = (const float*)d_in[7];
  const float* bih_bw1 = (const float*)d_in[8];
  const float* bhh_bw1 = (const float*)d_in[9];
  const float* Wih_fw2 = (const float*)d_in[10];
  const float* Whh_fw2 = (const float*)d_in[11];
  const float* bih_fw2 = (const float*)d_in[12];
  const float* bhh_fw2 = (const float*)d_in[13];
  const float* Wih_bw2 = (const float*)d_in[14];
  const float* Whh_bw2 = (const float*)d_in[15];
  const float* bih_bw2 = (const float*)d_in[16];
  const float* bhh_bw2 = (const float*)d_in[17];

  uint8_t* ws = (uint8_t*)d_ws;
  // ws: wpack1 [2][128][512] u32 (512KB) | wpack2 [2][192][512] u32 (768KB) |
  //     bias [4][512] f32 (8KB) | xf16 [B,T,64] u32 (16MB) | out1 [B,T,128] u32 (32MB)
  uint32_t* wpack1 = (uint32_t*)(ws + 0);
  uint32_t* wpack2 = (uint32_t*)(ws + 524288);
  float* biasws = (float*)(ws + 1310720);
  uint32_t* xf16 = (uint32_t*)(ws + 2097152);
  uint32_t* out1 = (uint32_t*)(ws + 18874368);
  float* fout = (float*)d_out;

  int n1 = 128 * 512 + 512, n2 = 192 * 512 + 512;
  prep_pack<<<(n1 + 255) / 256, 256, 0, stream>>>(Wih_fw1, Whh_fw1, bih_fw1, bhh_fw1,
                                                  wpack1, biasws, 128);
  prep_pack<<<(n1 + 255) / 256, 256, 0, stream>>>(Wih_bw1, Whh_bw1, bih_bw1, bhh_bw1,
                                                  wpack1 + 128 * 512, biasws + 512, 128);
  prep_pack<<<(n2 + 255) / 256, 256, 0, stream>>>(Wih_fw2, Whh_fw2, bih_fw2, bhh_fw2,
                                                  wpack2, biasws + 1024, 256);
  prep_pack<<<(n2 + 255) / 256, 256, 0, stream>>>(Wih_bw2, Whh_bw2, bih_bw2, bhh_bw2,
                                                  wpack2 + 192 * 512, biasws + 1536, 256);
  prep_x<<<(B_SZ * T_SEQ * 64) / 256, 256, 0, stream>>>((const float2*)x, xf16);

  scan_kernel<128, false><<<128, 512, 0, stream>>>(xf16, wpack1, biasws, out1, nullptr);
  scan_kernel<256, true><<<128, 512, 0, stream>>>(out1, wpack2, biasws + 1024, nullptr, fout);
}

// Round 5
// 2279.543 us; speedup vs baseline: 1.0786x; 1.0044x over previous
//
#include <hip/hip_runtime.h>
#include <hip/hip_fp16.h>
#include <stdint.h>

// BiLSTM 2-layer, B=64, T=1024, D=H=128.
// Round 5: rounds 2-4 all landed at VGPR_Count=116 -- the allocator targets
// 4 waves/EU on its own (cap 128) and spills the 192 loop-invariant weight
// regs to scratch, leaving us L2-BW-bound (~40 TB/s weight restream, 31%
// VALUBusy). __launch_bounds__ only sets the MIN waves/EU. Fix: pin min=max=2
// via amdgpu_waves_per_eu(2,2) -> hard 256-VGPR budget, no occupancy
// incentive to spill. Scalar asm pins kept as anti-remat insurance.
// Layout: 128 WGs (2 dir x 64 batch) x 512 thr; thread (j=tid&127, p=tid>>7)
// holds 4 gate rows {j+128r} over K-span p in VGPRs (f16x2, dot2 fp32-accum).

#define T_SEQ 1024
#define B_SZ  64

typedef _Float16 h2_t __attribute__((ext_vector_type(2)));

__device__ inline float dot2(uint32_t a, uint32_t b, float c) {
  return __builtin_amdgcn_fdot2(__builtin_bit_cast(h2_t, a),
                                __builtin_bit_cast(h2_t, b), c, false);
}

__device__ inline uint32_t pack2(float a, float b) {
  uint16_t ua = __builtin_bit_cast(uint16_t, (_Float16)a);
  uint16_t ub = __builtin_bit_cast(uint16_t, (_Float16)b);
  return (uint32_t)ua | ((uint32_t)ub << 16);
}

__device__ inline float sigmoidf_fast(float z) { return 1.0f / (1.0f + __expf(-z)); }

__device__ inline float tanhf_fast(float z) {
  float e = __expf(-2.0f * fabsf(z));
  float r = (1.0f - e) / (1.0f + e);
  return copysignf(r, z);
}

// wdst[w2*512 + g] = f16x2 of (Wcat[g][2*w2], Wcat[g][2*w2+1]), Wcat=[Wih|Whh].
__global__ void prep_pack(const float* __restrict__ Wih, const float* __restrict__ Whh,
                          const float* __restrict__ bih, const float* __restrict__ bhh,
                          uint32_t* __restrict__ wdst, float* __restrict__ bdst, int din) {
  int idx = blockIdx.x * 256 + threadIdx.x;
  int kw2 = din / 2 + 64;
  int nw = kw2 * 512;
  if (idx < nw) {
    int k2 = idx >> 9, g = idx & 511;
    float a, b;
    if (k2 < din / 2) {
      a = Wih[g * din + 2 * k2];
      b = Wih[g * din + 2 * k2 + 1];
    } else {
      int kk = k2 - din / 2;
      a = Whh[g * 128 + 2 * kk];
      b = Whh[g * 128 + 2 * kk + 1];
    }
    wdst[idx] = pack2(a, b);
  } else if (idx < nw + 512) {
    int g = idx - nw;
    bdst[g] = bih[g] + bhh[g];
  }
}

__global__ void prep_x(const float2* __restrict__ x2, uint32_t* __restrict__ xf16) {
  int idx = blockIdx.x * 256 + threadIdx.x;
  float2 v = x2[idx];
  xf16[idx] = pack2(v.x, v.y);
}

// One layer, both dirs. Block 512: thread (j = tid&127, p = tid>>7).
// xin: [B,T,DIN/2] u32 f16x2. wpack: [2][KW2][512] u32. bias: [2][512] f32.
template <int DIN, bool FINAL>
__global__ __launch_bounds__(512)
__attribute__((amdgpu_waves_per_eu(2, 2)))
void scan_kernel(
    const uint32_t* __restrict__ xin, const uint32_t* __restrict__ wpack,
    const float* __restrict__ bias, uint32_t* __restrict__ hout,
    float* __restrict__ fout) {
  constexpr int KW2 = DIN / 2 + 64;   // packed words per gate row
  constexpr int SPAN = KW2 / 4;       // words per thread per row
  constexpr int NQ = SPAN / 4;        // uint4 quads per row span
  constexpr int XW = DIN / 2;         // x words (h region at [XW, KW2))

  const int tid = threadIdx.x;
  const int j = tid & 127;
  const int p = tid >> 7;
  const int b = blockIdx.x & 63;
  const int dir = blockIdx.x >> 6;

  __shared__ __align__(16) uint32_t inbuf[2][KW2];  // [parity][ x | h ] f16x2
  __shared__ float psum[16][128];                   // [r*4+p][j]
  __shared__ float gatesL[4][128];                  // [gate q][j] activations

  // Per-thread weights: 4 gate rows x NQ quads, resident in VGPRs (budget 256
  // under waves_per_eu(2,2)). Scalar asm pins block rematerialization.
  uint4 wq[4][NQ];
  {
    const uint32_t* wp = wpack + (dir * KW2 + p * SPAN) * 512 + j;
#pragma unroll
    for (int r = 0; r < 4; r++) {
#pragma unroll
      for (int k = 0; k < NQ; k++) {
        wq[r][k].x = wp[(4 * k + 0) * 512 + r * 128];
        wq[r][k].y = wp[(4 * k + 1) * 512 + r * 128];
        wq[r][k].z = wp[(4 * k + 2) * 512 + r * 128];
        wq[r][k].w = wp[(4 * k + 3) * 512 + r * 128];
      }
    }
  }
#pragma unroll
  for (int r = 0; r < 4; r++)
#pragma unroll
    for (int k = 0; k < NQ; k++)
      asm volatile("" : "+v"(wq[r][k].x), "+v"(wq[r][k].y),
                        "+v"(wq[r][k].z), "+v"(wq[r][k].w));

  const float bias_pg = bias[dir * 512 + p * 128 + j];  // bias of gate p, row j

  // Init parity 0: x(t0) + h0 = 0.
  const int t0 = dir ? (T_SEQ - 1) : 0;
  if (tid < XW) inbuf[0][tid] = xin[(b * T_SEQ + t0) * XW + tid];
  if (tid >= XW && tid < KW2) inbuf[0][tid] = 0u;
  float c = 0.0f;
  __syncthreads();

  for (int s = 0; s < T_SEQ; s++) {
    const int t = dir ? (T_SEQ - 1 - s) : s;
    const int par = s & 1;

    // Prefetch next x into regs (p==1 group owns the store later).
    uint32_t xn = 0;
    if (p == 1 && j < XW && s + 1 < T_SEQ) {
      const int tn = dir ? (t - 1) : (t + 1);
      xn = xin[(b * T_SEQ + tn) * XW + j];
    }

    // Phase A: 4 partial dots over this thread's K-span (broadcast LDS reads).
    float a0 = 0.f, a1 = 0.f, a2 = 0.f, a3 = 0.f;
    const uint4* ib = (const uint4*)(&inbuf[par][p * SPAN]);
#pragma unroll
    for (int kk = 0; kk < NQ; kk++) {
      uint4 v = ib[kk];
      a0 = dot2(v.x, wq[0][kk].x, a0);
      a1 = dot2(v.x, wq[1][kk].x, a1);
      a2 = dot2(v.x, wq[2][kk].x, a2);
      a3 = dot2(v.x, wq[3][kk].x, a3);
      a0 = dot2(v.y, wq[0][kk].y, a0);
      a1 = dot2(v.y, wq[1][kk].y, a1);
      a2 = dot2(v.y, wq[2][kk].y, a2);
      a3 = dot2(v.y, wq[3][kk].y, a3);
      a0 = dot2(v.z, wq[0][kk].z, a0);
      a1 = dot2(v.z, wq[1][kk].z, a1);
      a2 = dot2(v.z, wq[2][kk].z, a2);
      a3 = dot2(v.z, wq[3][kk].z, a3);
      a0 = dot2(v.w, wq[0][kk].w, a0);
      a1 = dot2(v.w, wq[1][kk].w, a1);
      a2 = dot2(v.w, wq[2][kk].w, a2);
      a3 = dot2(v.w, wq[3][kk].w, a3);
    }
    psum[0 * 4 + p][j] = a0;
    psum[1 * 4 + p][j] = a1;
    psum[2 * 4 + p][j] = a2;
    psum[3 * 4 + p][j] = a3;
    __syncthreads();  // psums ready; all inbuf[par] reads done

    // Phase B: every thread reduces ONE gate (q = p) and applies activation.
    {
      float ssum = bias_pg + psum[p * 4 + 0][j] + psum[p * 4 + 1][j] +
                   psum[p * 4 + 2][j] + psum[p * 4 + 3][j];
      gatesL[p][j] = (p == 2) ? tanhf_fast(ssum) : sigmoidf_fast(ssum);
    }
    if (p == 1 && j < XW && s + 1 < T_SEQ) {
      inbuf[par ^ 1][j] = xn;  // x region of other parity (nobody reads it now)
    }
    __syncthreads();  // activations ready

    // Phase C: p==0 quarter updates c,h and writes h / output.
    if (p == 0) {
      float iv = gatesL[0][j], fv = gatesL[1][j], gv = gatesL[2][j], ov = gatesL[3][j];
      c = fv * c + iv * gv;
      float h = ov * tanhf_fast(c);
      uint16_t hu = __builtin_bit_cast(uint16_t, (_Float16)h);
      ((uint16_t*)(&inbuf[par ^ 1][XW]))[j] = hu;  // h for next step's parity
      if (FINAL) {
        fout[(b * T_SEQ + t) * 256 + dir * 128 + j] = h;
      } else {
        ((uint16_t*)hout)[(b * T_SEQ + t) * 256 + dir * 128 + j] = hu;
      }
    }
    __syncthreads();  // h + next-x visible before next dot phase
  }
}

extern "C" void kernel_launch(void* const* d_in, const int* in_sizes, int n_in,
                              void* d_out, int out_size, void* d_ws, size_t ws_size,
                              hipStream_t stream) {
  const float* x = (const float*)d_in[0];
  const float* Wih_fw1 = (const float*)d_in[2];
  const float* Whh_fw1 = (const float*)d_in[3];
  const float* bih_fw1 = (const float*)d_in[4];
  const float* bhh_fw1 = (const float*)d_in[5];
  const float* Wih_bw1 = (const float*)d_in[6];
  const float* Whh_bw1 = (const float*)d_in[7];
  const float* bih_bw1 = (const float*)d_in[8];
  const float* bhh_bw1 = (const float*)d_in[9];
  const float* Wih_fw2 = (const float*)d_in[10];
  const float* Whh_fw2 = (const float*)d_in[11];
  const float* bih_fw2 = (const float*)d_in[12];
  const float* bhh_fw2 = (const float*)d_in[13];
  const float* Wih_bw2 = (const float*)d_in[14];
  const float* Whh_bw2 = (const float*)d_in[15];
  const float* bih_bw2 = (const float*)d_in[16];
  const float* bhh_bw2 = (const float*)d_in[17];

  uint8_t* ws = (uint8_t*)d_ws;
  // ws: wpack1 [2][128][512] u32 (512KB) | wpack2 [2][192][512] u32 (768KB) |
  //     bias [4][512] f32 (8KB) | xf16 [B,T,64] u32 (16MB) | out1 [B,T,128] u32 (32MB)
  uint32_t* wpack1 = (uint32_t*)(ws + 0);
  uint32_t* wpack2 = (uint32_t*)(ws + 524288);
  float* biasws = (float*)(ws + 1310720);
  uint32_t* xf16 = (uint32_t*)(ws + 2097152);
  uint32_t* out1 = (uint32_t*)(ws + 18874368);
  float* fout = (float*)d_out;

  int n1 = 128 * 512 + 512, n2 = 192 * 512 + 512;
  prep_pack<<<(n1 + 255) / 256, 256, 0, stream>>>(Wih_fw1, Whh_fw1, bih_fw1, bhh_fw1,
                                                  wpack1, biasws, 128);
  prep_pack<<<(n1 + 255) / 256, 256, 0, stream>>>(Wih_bw1, Whh_bw1, bih_bw1, bhh_bw1,
                                                  wpack1 + 128 * 512, biasws + 512, 128);
  prep_pack<<<(n2 + 255) / 256, 256, 0, stream>>>(Wih_fw2, Whh_fw2, bih_fw2, bhh_fw2,
                                                  wpack2, biasws + 1024, 256);
  prep_pack<<<(n2 + 255) / 256, 256, 0, stream>>>(Wih_bw2, Whh_bw2, bih_bw2, bhh_bw2,
                                                  wpack2 + 192 * 512, biasws + 1536, 256);
  prep_x<<<(B_SZ * T_SEQ * 64) / 256, 256, 0, stream>>>((const float2*)x, xf16);

  scan_kernel<128, false><<<128, 512, 0, stream>>>(xf16, wpack1, biasws, out1, nullptr);
  scan_kernel<256, true><<<128, 512, 0, stream>>>(out1, wpack2, biasws + 1024, nullptr, fout);
}

// Round 6
// 1668.079 us; speedup vs baseline: 1.4740x; 1.3666x over previous
//
#include <hip/hip_runtime.h>
#include <hip/hip_fp16.h>
#include <stdint.h>

// BiLSTM 2-layer, B=64, T=1024, D=H=128.
// Round 6: three rounds proved the allocator will not hold 192 weight
// words/thread (VGPR_Count pinned at 116; weights spill to scratch; kernel is
// L2/scratch-BW-bound at ~1.27ms/scan). Restructure instead:
//   gates_t = xg_t + Whh*h_{t-1},  xg = A @ Wih^T + b  (NO recurrence)
// 1) xg precomputed for all timesteps with an MFMA f16 GEMM (16x16x32_f16,
//    B^T layout: both A and B fragments are b128 reads of row-major f16).
// 2) scan keeps only Whh resident: 64 f16x2 words/thread -- fits under the
//    allocator's 128-VGPR target, no spill, no tricks needed.

#define T_SEQ 1024
#define B_SZ  64
#define M_TOT 65536  // B*T rows

typedef _Float16 h2_t __attribute__((ext_vector_type(2)));
typedef _Float16 f16x8 __attribute__((ext_vector_type(8)));
typedef float f32x4 __attribute__((ext_vector_type(4)));

__device__ inline float dot2(uint32_t a, uint32_t b, float c) {
  return __builtin_amdgcn_fdot2(__builtin_bit_cast(h2_t, a),
                                __builtin_bit_cast(h2_t, b), c, false);
}

__device__ inline uint32_t pack2(float a, float b) {
  uint16_t ua = __builtin_bit_cast(uint16_t, (_Float16)a);
  uint16_t ub = __builtin_bit_cast(uint16_t, (_Float16)b);
  return (uint32_t)ua | ((uint32_t)ub << 16);
}

__device__ inline float sigmoidf_fast(float z) { return 1.0f / (1.0f + __expf(-z)); }

__device__ inline float tanhf_fast(float z) {
  float e = __expf(-2.0f * fabsf(z));
  float r = (1.0f - e) / (1.0f + e);
  return copysignf(r, z);
}

// ---------- prep kernels ----------

// Whh [512][128] f32 -> wh [64 kw][512 g] u32 (f16x2 along k)
__global__ void prep_whh(const float* __restrict__ Whh, uint32_t* __restrict__ dst) {
  int idx = blockIdx.x * 256 + threadIdx.x;  // < 64*512
  int kw = idx >> 9, g = idx & 511;
  dst[idx] = pack2(Whh[g * 128 + 2 * kw], Whh[g * 128 + 2 * kw + 1]);
}

// Wih [512][2*KW] f32 -> Bt [512 g][KW kw] u32 row-major (= B^T rows for MFMA)
template <int KW>
__global__ void prep_bt(const float* __restrict__ Wih, uint32_t* __restrict__ dst) {
  int idx = blockIdx.x * 256 + threadIdx.x;  // < 512*KW
  constexpr int SH = (KW == 64) ? 6 : 7;
  int g = idx >> SH, kw = idx & (KW - 1);
  dst[idx] = pack2(Wih[g * (2 * KW) + 2 * kw], Wih[g * (2 * KW) + 2 * kw + 1]);
}

__global__ void prep_biasc(const float* __restrict__ bih, const float* __restrict__ bhh,
                           float* __restrict__ dst) {
  int idx = blockIdx.x * 256 + threadIdx.x;  // < 512
  if (idx < 512) dst[idx] = bih[idx] + bhh[idx];
}

// x [B,T,128] f32 -> packed f16x2 [M][64] u32
__global__ void prep_x(const float2* __restrict__ x2, uint32_t* __restrict__ xf16) {
  int idx = blockIdx.x * 256 + threadIdx.x;
  float2 v = x2[idx];
  xf16[idx] = pack2(v.x, v.y);
}

// ---------- xg GEMM: xg[cell][m][512] f16 = A[m][:] . Wih_cell^T + bias ----------
// A: [M][KW] u32 (f16x2, row-major). Bt: [1024 n][KW] u32 (n = cell*512+g).
// Grid (16 n-tiles, 1024 m-tiles) x 256 thr. 64x64 tile, 4 waves of 32x32.
template <int KW>
__global__ __launch_bounds__(256) void xg_gemm(
    const uint32_t* __restrict__ A, const uint32_t* __restrict__ Bt,
    const float* __restrict__ biascat, uint16_t* __restrict__ xg) {
  const int n0 = blockIdx.x * 64;
  const int m0 = blockIdx.y * 64;
  const int tid = threadIdx.x;
  __shared__ uint32_t At[64][36];   // stride 36 words: 16B-aligned quads, 2-way banks
  __shared__ uint32_t Bts[64][36];
  const int lr = tid >> 2, lq = tid & 3;
  const int wave = tid >> 6, lane = tid & 63;
  const int wm = wave >> 1, wn = wave & 1;
  const int q = lane >> 4, ln16 = lane & 15;
  f32x4 acc[2][2] = {};
  for (int kb = 0; kb < KW; kb += 16) {
    uint4 av = *(const uint4*)&A[(size_t)(m0 + lr) * KW + kb + lq * 4];
    uint4 bv = *(const uint4*)&Bt[(size_t)(n0 + lr) * KW + kb + lq * 4];
    __syncthreads();  // previous iteration's fragment reads complete
    *(uint4*)&At[lr][lq * 4] = av;
    *(uint4*)&Bts[lr][lq * 4] = bv;
    __syncthreads();
#pragma unroll
    for (int mi = 0; mi < 2; mi++) {
      f16x8 af = *(const f16x8*)&At[wm * 32 + mi * 16 + ln16][q * 4];
#pragma unroll
      for (int ni = 0; ni < 2; ni++) {
        f16x8 bf = *(const f16x8*)&Bts[wn * 32 + ni * 16 + ln16][q * 4];
        acc[mi][ni] = __builtin_amdgcn_mfma_f32_16x16x32_f16(af, bf, acc[mi][ni], 0, 0, 0);
      }
    }
  }
  // D layout (verified m89/m91): col = lane&15, row = (lane>>4)*4 + reg
#pragma unroll
  for (int mi = 0; mi < 2; mi++)
#pragma unroll
    for (int ni = 0; ni < 2; ni++) {
      int n = n0 + wn * 32 + ni * 16 + ln16;
      int cell = n >> 9, g = n & 511;
      float bs = biascat[n];
#pragma unroll
      for (int i = 0; i < 4; i++) {
        int m = m0 + wm * 32 + mi * 16 + q * 4 + i;
        float v = acc[mi][ni][i] + bs;
        xg[((size_t)cell * M_TOT + m) * 512 + g] =
            __builtin_bit_cast(uint16_t, (_Float16)v);
      }
    }
}

// ---------- scan: gates_t = xg_t + Whh.h_{t-1}, K = 64 words of h only ----------
// 128 WGs (dir*64+b) x 512 thr; thread (j=tid&127, p=tid>>7) computes gate rows
// {j+128r} over h-span [p*16, p*16+16). wh2: [2 dir][64 kw][512 g] u32.
template <bool FINAL>
__global__ __launch_bounds__(512) void scan_kernel(
    const uint16_t* __restrict__ xg, const uint32_t* __restrict__ wh2,
    uint16_t* __restrict__ hout, float* __restrict__ fout) {
  const int tid = threadIdx.x;
  const int j = tid & 127;
  const int p = tid >> 7;
  const int b = blockIdx.x & 63;
  const int dir = blockIdx.x >> 6;

  __shared__ __align__(16) uint32_t hbuf[2][64];  // [parity][h f16x2]
  __shared__ float psum[16][128];                 // [r*4+p][j]
  __shared__ float gatesL[4][128];                // [r][j]

  // Whh slice: 4 rows x 16 words = 64 VGPRs. Fits the allocator's budget.
  uint32_t wq[4][16];
  {
    const uint32_t* wp = wh2 + (size_t)dir * 64 * 512;
#pragma unroll
    for (int r = 0; r < 4; r++)
#pragma unroll
      for (int w = 0; w < 16; w++) wq[r][w] = wp[(p * 16 + w) * 512 + j + 128 * r];
  }
#pragma unroll
  for (int r = 0; r < 4; r++)
#pragma unroll
    for (int w = 0; w < 16; w++) asm volatile("" : "+v"(wq[r][w]));

  const uint16_t* xgp = xg + ((size_t)dir * M_TOT + b * T_SEQ) * 512;

  if (tid < 64) hbuf[0][tid] = 0u;
  float c = 0.0f;
  const int t0 = dir ? (T_SEQ - 1) : 0;
  uint16_t xg_cur = xgp[(size_t)t0 * 512 + tid];
  __syncthreads();

  for (int s = 0; s < T_SEQ; s++) {
    const int t = dir ? (T_SEQ - 1 - s) : s;
    const int par = s & 1;

    // prefetch next step's xg (fully coalesced: one u16 per thread)
    uint16_t xg_nxt = 0;
    if (s + 1 < T_SEQ) {
      const int tn = dir ? (t - 1) : (t + 1);
      xg_nxt = xgp[(size_t)tn * 512 + tid];
    }

    // Phase A: partial dots over h-span p (wave-uniform b128 broadcast reads)
    float a0 = 0.f, a1 = 0.f, a2 = 0.f, a3 = 0.f;
    const uint4* ib = (const uint4*)(&hbuf[par][p * 16]);
#pragma unroll
    for (int kk = 0; kk < 4; kk++) {
      uint4 v = ib[kk];
      a0 = dot2(v.x, wq[0][4 * kk + 0], a0);
      a1 = dot2(v.x, wq[1][4 * kk + 0], a1);
      a2 = dot2(v.x, wq[2][4 * kk + 0], a2);
      a3 = dot2(v.x, wq[3][4 * kk + 0], a3);
      a0 = dot2(v.y, wq[0][4 * kk + 1], a0);
      a1 = dot2(v.y, wq[1][4 * kk + 1], a1);
      a2 = dot2(v.y, wq[2][4 * kk + 1], a2);
      a3 = dot2(v.y, wq[3][4 * kk + 1], a3);
      a0 = dot2(v.z, wq[0][4 * kk + 2], a0);
      a1 = dot2(v.z, wq[1][4 * kk + 2], a1);
      a2 = dot2(v.z, wq[2][4 * kk + 2], a2);
      a3 = dot2(v.z, wq[3][4 * kk + 2], a3);
      a0 = dot2(v.w, wq[0][4 * kk + 3], a0);
      a1 = dot2(v.w, wq[1][4 * kk + 3], a1);
      a2 = dot2(v.w, wq[2][4 * kk + 3], a2);
      a3 = dot2(v.w, wq[3][4 * kk + 3], a3);
    }
    psum[0 * 4 + p][j] = a0;
    psum[1 * 4 + p][j] = a1;
    psum[2 * 4 + p][j] = a2;
    psum[3 * 4 + p][j] = a3;
    __syncthreads();

    // Phase B: thread (j,p) reduces gate row j+128p; xg term folded in here.
    {
      float xgv = (float)__builtin_bit_cast(_Float16, xg_cur);
      float ssum = xgv + psum[p * 4 + 0][j] + psum[p * 4 + 1][j] +
                   psum[p * 4 + 2][j] + psum[p * 4 + 3][j];
      gatesL[p][j] = (p == 2) ? tanhf_fast(ssum) : sigmoidf_fast(ssum);
    }
    __syncthreads();

    // Phase C: p==0 updates c,h; writes h (f16) and the layer output.
    if (p == 0) {
      float iv = gatesL[0][j], fv = gatesL[1][j], gv = gatesL[2][j], ov = gatesL[3][j];
      c = fv * c + iv * gv;
      float h = ov * tanhf_fast(c);
      uint16_t hu = __builtin_bit_cast(uint16_t, (_Float16)h);
      ((uint16_t*)(&hbuf[par ^ 1][0]))[j] = hu;
      if (FINAL) {
        fout[(size_t)(b * T_SEQ + t) * 256 + dir * 128 + j] = h;
      } else {
        hout[(size_t)(b * T_SEQ + t) * 256 + dir * 128 + j] = hu;
      }
    }
    xg_cur = xg_nxt;
    __syncthreads();
  }
}

extern "C" void kernel_launch(void* const* d_in, const int* in_sizes, int n_in,
                              void* d_out, int out_size, void* d_ws, size_t ws_size,
                              hipStream_t stream) {
  const float* x = (const float*)d_in[0];
  const float* Wih_fw1 = (const float*)d_in[2];
  const float* Whh_fw1 = (const float*)d_in[3];
  const float* bih_fw1 = (const float*)d_in[4];
  const float* bhh_fw1 = (const float*)d_in[5];
  const float* Wih_bw1 = (const float*)d_in[6];
  const float* Whh_bw1 = (const float*)d_in[7];
  const float* bih_bw1 = (const float*)d_in[8];
  const float* bhh_bw1 = (const float*)d_in[9];
  const float* Wih_fw2 = (const float*)d_in[10];
  const float* Whh_fw2 = (const float*)d_in[11];
  const float* bih_fw2 = (const float*)d_in[12];
  const float* bhh_fw2 = (const float*)d_in[13];
  const float* Wih_bw2 = (const float*)d_in[14];
  const float* Whh_bw2 = (const float*)d_in[15];
  const float* bih_bw2 = (const float*)d_in[16];
  const float* bhh_bw2 = (const float*)d_in[17];

  uint8_t* ws = (uint8_t*)d_ws;
  // ws layout (bytes):
  //   0        : whbuf   [4 cells][64][512] u32     512 KB
  //   524288   : btbuf1  [2*512][64]  u32           256 KB
  //   786432   : btbuf2  [2*512][128] u32           512 KB
  //   1310720  : biascat [2 layers][1024] f32         8 KB
  //   2097152  : xf16    [M][64] u32                 16 MB
  //   18874368 : out1    [M][128] u32 (f16x2)        32 MB
  //   52428800 : xg      [2][M][512] f16            128 MB   (reused L1 then L2)
  uint32_t* whbuf = (uint32_t*)(ws + 0);
  uint32_t* btbuf1 = (uint32_t*)(ws + 524288);
  uint32_t* btbuf2 = (uint32_t*)(ws + 786432);
  float* biascat = (float*)(ws + 1310720);
  uint32_t* xf16 = (uint32_t*)(ws + 2097152);
  uint32_t* out1 = (uint32_t*)(ws + 18874368);
  uint16_t* xgbuf = (uint16_t*)(ws + 52428800);
  float* fout = (float*)d_out;

  // --- weight / bias / input packing ---
  prep_whh<<<128, 256, 0, stream>>>(Whh_fw1, whbuf + 0 * 32768);
  prep_whh<<<128, 256, 0, stream>>>(Whh_bw1, whbuf + 1 * 32768);
  prep_whh<<<128, 256, 0, stream>>>(Whh_fw2, whbuf + 2 * 32768);
  prep_whh<<<128, 256, 0, stream>>>(Whh_bw2, whbuf + 3 * 32768);
  prep_bt<64><<<128, 256, 0, stream>>>(Wih_fw1, btbuf1 + 0);
  prep_bt<64><<<128, 256, 0, stream>>>(Wih_bw1, btbuf1 + 512 * 64);
  prep_bt<128><<<256, 256, 0, stream>>>(Wih_fw2, btbuf2 + 0);
  prep_bt<128><<<256, 256, 0, stream>>>(Wih_bw2, btbuf2 + 512 * 128);
  prep_biasc<<<2, 256, 0, stream>>>(bih_fw1, bhh_fw1, biascat + 0);
  prep_biasc<<<2, 256, 0, stream>>>(bih_bw1, bhh_bw1, biascat + 512);
  prep_biasc<<<2, 256, 0, stream>>>(bih_fw2, bhh_fw2, biascat + 1024);
  prep_biasc<<<2, 256, 0, stream>>>(bih_bw2, bhh_bw2, biascat + 1536);
  prep_x<<<(B_SZ * T_SEQ * 64) / 256, 256, 0, stream>>>((const float2*)x, xf16);

  // --- layer 1: xg GEMM + scan ---
  xg_gemm<64><<<dim3(16, 1024), 256, 0, stream>>>(xf16, btbuf1, biascat, xgbuf);
  scan_kernel<false><<<128, 512, 0, stream>>>(xgbuf, whbuf + 0, (uint16_t*)out1, nullptr);

  // --- layer 2: xg GEMM (reads out1) + scan -> d_out ---
  xg_gemm<128><<<dim3(16, 1024), 256, 0, stream>>>(out1, btbuf2, biascat + 1024, xgbuf);
  scan_kernel<true><<<128, 512, 0, stream>>>(xgbuf, whbuf + 2 * 32768, nullptr, fout);
}